// Round 10
// baseline (63.966 us; speedup 1.0000x reference)
//
#include <hip/hip_runtime.h>
#include <math.h>

// Problem constants
#define BB 512      // batch (edges)
#define NN 4096     // nodes
#define LL 128      // feature dim
#define IN_DIM 385  // 3*L + ND
#define NK4_1 97    // ceil(IN_DIM/4) k-groups, layer 1
#define NK4_2 32    // LL/4 k-groups, layer 2 / GRU
#define EPB 2       // edges per block (edge phase)
#define NBLK 512    // fused kernel blocks (co-resident: 2048 waves << 8192)

// ---------------------------------------------------------------------------
// Workspace layout (float offsets, float4-aligned)
// ---------------------------------------------------------------------------
#define OFF_MSG   0                           // msg_sum (N*L)
#define OFF_CNT   (OFF_MSG + NN * LL)         // cnt (N)
#define OFF_COUNT (OFF_CNT + NN)              // seen_count (1 int) + pad
#define OFF_LIST  (OFF_COUNT + 4)             // seen list (1024 ints)
#define OFF_DONE  (OFF_LIST + 1024)           // arrive counter (1 int) + pad
#define OFF_W1PS  (OFF_DONE + 4)              // src_w1 packed f4[k4*128+j]
#define OFF_W1PT  (OFF_W1PS + NK4_1 * LL * 4)
#define OFF_W2PS  (OFF_W1PT + NK4_1 * LL * 4)
#define OFF_W2PT  (OFF_W2PS + NK4_2 * LL * 4)
#define OFF_WIHP  (OFF_W2PT + NK4_2 * LL * 4) // f4[(gate*32+k4)*128+j]
#define OFF_WHHP  (OFF_WIHP + 3 * NK4_2 * LL * 4)

#define AGENT __HIP_MEMORY_SCOPE_AGENT

// ---------------------------------------------------------------------------
// Prep: zero accumulators + arrive counter, pack ALL weights f4[k4*128+j]
// (lane-coalesced). Kernel boundary makes these visible/coherent to the
// fused kernel on all XCDs.
// ---------------------------------------------------------------------------
__global__ __launch_bounds__(256) void prep_kernel(
    const float* __restrict__ sw1, const float* __restrict__ tw1,
    const float* __restrict__ sw2, const float* __restrict__ tw2,
    const float* __restrict__ wih, const float* __restrict__ whh,
    float* __restrict__ ws)
{
    const int i = blockIdx.x * 256 + threadIdx.x;
    const int stride = gridDim.x * 256;

    float4* msg4 = (float4*)(ws + OFF_MSG);
    const float4 z4 = make_float4(0.f, 0.f, 0.f, 0.f);
    for (int idx = i; idx < NN * LL / 4; idx += stride)
        msg4[idx] = z4;
    for (int idx = i; idx < NN; idx += stride)
        ws[OFF_CNT + idx] = 0.0f;
    if (i == 0) {
        ((int*)ws)[OFF_COUNT] = 0;
        ((int*)ws)[OFF_DONE] = 0;
    }

    float4* w1ps = (float4*)(ws + OFF_W1PS);
    float4* w1pt = (float4*)(ws + OFF_W1PT);
    for (int idx = i; idx < NK4_1 * LL; idx += stride) {
        const int k4 = idx >> 7, j = idx & 127;
        const int k = k4 * 4;
        float4 a, b;
        a.x = sw1[j * IN_DIM + k];     b.x = tw1[j * IN_DIM + k];
        a.y = (k + 1 < IN_DIM) ? sw1[j * IN_DIM + k + 1] : 0.f;
        b.y = (k + 1 < IN_DIM) ? tw1[j * IN_DIM + k + 1] : 0.f;
        a.z = (k + 2 < IN_DIM) ? sw1[j * IN_DIM + k + 2] : 0.f;
        b.z = (k + 2 < IN_DIM) ? tw1[j * IN_DIM + k + 2] : 0.f;
        a.w = (k + 3 < IN_DIM) ? sw1[j * IN_DIM + k + 3] : 0.f;
        b.w = (k + 3 < IN_DIM) ? tw1[j * IN_DIM + k + 3] : 0.f;
        w1ps[idx] = a; w1pt[idx] = b;
    }
    float4* w2ps = (float4*)(ws + OFF_W2PS);
    float4* w2pt = (float4*)(ws + OFF_W2PT);
    for (int idx = i; idx < NK4_2 * LL; idx += stride) {
        const int k4 = idx >> 7, j = idx & 127;
        const int k = k4 * 4;
        w2ps[idx] = make_float4(sw2[j * LL + k], sw2[j * LL + k + 1],
                                sw2[j * LL + k + 2], sw2[j * LL + k + 3]);
        w2pt[idx] = make_float4(tw2[j * LL + k], tw2[j * LL + k + 1],
                                tw2[j * LL + k + 2], tw2[j * LL + k + 3]);
    }
    float4* wihp = (float4*)(ws + OFF_WIHP);
    float4* whhp = (float4*)(ws + OFF_WHHP);
    for (int idx = i; idx < 3 * NK4_2 * LL; idx += stride) {
        const int j = idx & 127;
        const int gk = idx >> 7;
        const int gate = gk >> 5, k4 = gk & 31;
        const int row = gate * LL + j, k = k4 * 4;
        wihp[idx] = make_float4(wih[row * LL + k], wih[row * LL + k + 1],
                                wih[row * LL + k + 2], wih[row * LL + k + 3]);
        whhp[idx] = make_float4(whh[row * LL + k], whh[row * LL + k + 1],
                                whh[row * LL + k + 2], whh[row * LL + k + 3]);
    }
}

// ---------------------------------------------------------------------------
// Fused kernel: phase 1 = edge messages (r9-proven body, 512 blocks);
// arrive/spin barrier (all blocks co-resident); phase 2 = passthrough copy
// of unseen rows (8 rows/block, exact cover) + GRU (2 list slots/block).
// Cross-phase data (msg/cnt/list/count) written with device-scope atomics,
// read with agent-scope atomic loads (XCD-L2-coherence safe).
// ---------------------------------------------------------------------------
__global__ __launch_bounds__(256) void fused_kernel(
    const float* __restrict__ x,        // (B, N, 1)
    const float* __restrict__ memory,   // (N, L)
    const float* __restrict__ delta_t,  // (B, N, L)
    const float* __restrict__ sb1, const float* __restrict__ sb2,
    const float* __restrict__ tb1, const float* __restrict__ tb2,
    const float* __restrict__ bih, const float* __restrict__ bhh,
    const int* __restrict__ source, const int* __restrict__ target,
    float* __restrict__ ws, float* __restrict__ out)
{
    const int tid = threadIdx.x;
    const int bid = blockIdx.x;
    const int g   = tid >> 7;            // group 0/1
    const int j   = tid & 127;           // feature lane

    __shared__ float h1[LL][EPB];
    __shared__ float part1[2][EPB][LL];
    __shared__ float part2[2][EPB][LL];

    // ======================= Phase 1: edge messages =======================
    const int side  = bid & 1;
    const int chunk = bid >> 1;
    const int eg0 = chunk * EPB, eg1 = eg0 + 1;
    const int s0 = source[eg0], t0 = target[eg0];
    const int s1 = source[eg1], t1 = target[eg1];
    const int node0  = side ? t0 : s0, other0 = side ? s0 : t0;
    const int node1  = side ? t1 : s1, other1 = side ? s1 : t1;

    {
        const float4* w1p = (const float4*)(ws + (side ? OFF_W1PT : OFF_W1PS));
        const float4* w2p = (const float4*)(ws + (side ? OFF_W2PT : OFF_W2PS));
        const float* b1  = side ? tb1 : sb1;
        const float* b2  = side ? tb2 : sb2;

        // Layer 1, segment-split (block-uniform input addresses).
        {
            float a0 = 0.f, a1 = 0.f;
            const float* dA = delta_t + ((size_t)eg0 * NN + node0) * LL;
            const float* dB = delta_t + ((size_t)eg1 * NN + node1) * LL;
            if (g == 0) {
                const float* pA = memory + (size_t)node0 * LL;
                const float* pB = memory + (size_t)node1 * LL;
                #pragma unroll 4
                for (int k4 = 0; k4 < 32; ++k4) {
                    const float4 w  = w1p[k4 * LL + j];
                    const float4 iA = *(const float4*)(pA + 4 * k4);
                    const float4 iB = *(const float4*)(pB + 4 * k4);
                    a0 = fmaf(w.x, iA.x, a0); a1 = fmaf(w.x, iB.x, a1);
                    a0 = fmaf(w.y, iA.y, a0); a1 = fmaf(w.y, iB.y, a1);
                    a0 = fmaf(w.z, iA.z, a0); a1 = fmaf(w.z, iB.z, a1);
                    a0 = fmaf(w.w, iA.w, a0); a1 = fmaf(w.w, iB.w, a1);
                }
                #pragma unroll 4
                for (int k4 = 64; k4 < 80; ++k4) {
                    const float4 w  = w1p[k4 * LL + j];
                    const float4 iA = *(const float4*)(dA + 4 * (k4 - 64));
                    const float4 iB = *(const float4*)(dB + 4 * (k4 - 64));
                    a0 = fmaf(w.x, iA.x, a0); a1 = fmaf(w.x, iB.x, a1);
                    a0 = fmaf(w.y, iA.y, a0); a1 = fmaf(w.y, iB.y, a1);
                    a0 = fmaf(w.z, iA.z, a0); a1 = fmaf(w.z, iB.z, a1);
                    a0 = fmaf(w.w, iA.w, a0); a1 = fmaf(w.w, iB.w, a1);
                }
            } else {
                const float* pA = memory + (size_t)other0 * LL;
                const float* pB = memory + (size_t)other1 * LL;
                #pragma unroll 4
                for (int k4 = 32; k4 < 64; ++k4) {
                    const float4 w  = w1p[k4 * LL + j];
                    const float4 iA = *(const float4*)(pA + 4 * (k4 - 32));
                    const float4 iB = *(const float4*)(pB + 4 * (k4 - 32));
                    a0 = fmaf(w.x, iA.x, a0); a1 = fmaf(w.x, iB.x, a1);
                    a0 = fmaf(w.y, iA.y, a0); a1 = fmaf(w.y, iB.y, a1);
                    a0 = fmaf(w.z, iA.z, a0); a1 = fmaf(w.z, iB.z, a1);
                    a0 = fmaf(w.w, iA.w, a0); a1 = fmaf(w.w, iB.w, a1);
                }
                #pragma unroll 4
                for (int k4 = 80; k4 < 96; ++k4) {
                    const float4 w  = w1p[k4 * LL + j];
                    const float4 iA = *(const float4*)(dA + 4 * (k4 - 64));
                    const float4 iB = *(const float4*)(dB + 4 * (k4 - 64));
                    a0 = fmaf(w.x, iA.x, a0); a1 = fmaf(w.x, iB.x, a1);
                    a0 = fmaf(w.y, iA.y, a0); a1 = fmaf(w.y, iB.y, a1);
                    a0 = fmaf(w.z, iA.z, a0); a1 = fmaf(w.z, iB.z, a1);
                    a0 = fmaf(w.w, iA.w, a0); a1 = fmaf(w.w, iB.w, a1);
                }
                {   // k = 384: x input (w1p[96].yzw zero-padded)
                    const float4 w = w1p[96 * LL + j];
                    a0 = fmaf(w.x, x[(size_t)eg0 * NN + node0], a0);
                    a1 = fmaf(w.x, x[(size_t)eg1 * NN + node1], a1);
                }
            }
            part1[g][0][j] = a0;
            part1[g][1][j] = a1;
        }
        __syncthreads();

        h1[j][g] = fmaxf(part1[0][g][j] + part1[1][g][j] + b1[j], 0.0f);
        __syncthreads();

        // Layer 2
        {
            const int k40 = g * 16, k41 = k40 + 16;
            float a0 = 0.f, a1 = 0.f;
            #pragma unroll 4
            for (int k4 = k40; k4 < k41; ++k4) {
                const float4 w  = w2p[k4 * LL + j];
                const float4 h0 = *(const float4*)&h1[k4 * 4][0];
                const float4 h2 = *(const float4*)&h1[k4 * 4 + 2][0];
                a0 = fmaf(w.x, h0.x, a0); a1 = fmaf(w.x, h0.y, a1);
                a0 = fmaf(w.y, h0.z, a0); a1 = fmaf(w.y, h0.w, a1);
                a0 = fmaf(w.z, h2.x, a0); a1 = fmaf(w.z, h2.y, a1);
                a0 = fmaf(w.w, h2.z, a0); a1 = fmaf(w.w, h2.w, a1);
            }
            part2[g][0][j] = a0;
            part2[g][1][j] = a1;
        }
        __syncthreads();

        {
            const int node = g ? node1 : node0;
            const float m = part2[0][g][j] + part2[1][g][j] + b2[j];
            atomicAdd(ws + OFF_MSG + (size_t)node * LL + j, m);
        }
        if (tid < EPB) {
            const int node = tid ? node1 : node0;
            const float old = atomicAdd(ws + OFF_CNT + node, 1.0f);
            if (old == 0.0f) {
                const int pos = atomicAdd((int*)ws + OFF_COUNT, 1);
                ((int*)ws)[OFF_LIST + pos] = node;   // unique nodes only
            }
        }
    }

    // =================== Arrive / spin barrier (all 512) ===================
    __syncthreads();                       // drains vmcnt: block's atomics done
    if (tid == 0) {
        __threadfence();
        atomicAdd((int*)ws + OFF_DONE, 1);
        while (__hip_atomic_load((int*)ws + OFF_DONE, __ATOMIC_ACQUIRE, AGENT)
               < NBLK)
            __builtin_amdgcn_s_sleep(1);
    }
    __syncthreads();

    // ============ Phase 2a: passthrough copy of unseen rows ============
    {
        const int node = bid * 8 + (tid >> 5);     // 512*8 = 4096 exact
        const int f4i  = tid & 31;
        const float c = __hip_atomic_load(ws + OFF_CNT + node,
                                          __ATOMIC_RELAXED, AGENT);
        if (c == 0.0f)
            ((float4*)out)[(size_t)node * 32 + f4i] =
                ((const float4*)memory)[(size_t)node * 32 + f4i];
    }

    // ============ Phase 2b: GRU, 2 list slots per block ============
    {
        const int scount = __hip_atomic_load((const int*)ws + OFF_COUNT,
                                             __ATOMIC_RELAXED, AGENT);
        const int base = bid * 2;
        if (base >= scount) return;
        const int nact = min(2, scount - base);

        __shared__ float ah[LL][4];          // [k][0..1]=agg, [2..3]=h
        __shared__ float gates[6][2][LL];
        __shared__ int   nodes_sh[2];

        int nd[2];
        nd[0] = __hip_atomic_load((const int*)ws + OFF_LIST + base,
                                  __ATOMIC_RELAXED, AGENT);
        nd[1] = (nact > 1)
              ? __hip_atomic_load((const int*)ws + OFF_LIST + base + 1,
                                  __ATOMIC_RELAXED, AGENT)
              : nd[0];
        if (tid < 2) nodes_sh[tid] = nd[tid];

        if (g == 0) {
            #pragma unroll
            for (int s = 0; s < 2; ++s) {
                const float c = __hip_atomic_load(ws + OFF_CNT + nd[s],
                                                  __ATOMIC_RELAXED, AGENT);
                const float m = __hip_atomic_load(
                    ws + OFF_MSG + (size_t)nd[s] * LL + j,
                    __ATOMIC_RELAXED, AGENT);
                ah[j][s] = m / c;
            }
        } else {
            #pragma unroll
            for (int s = 0; s < 2; ++s)
                ah[j][2 + s] = memory[(size_t)nd[s] * LL + j];
        }
        __syncthreads();

        const float4* wp = (const float4*)(ws + (g ? OFF_WHHP : OFF_WIHP));
        float a0[2] = {}, a1[2] = {}, a2[2] = {};
        #pragma unroll 2
        for (int k4 = 0; k4 < NK4_2; ++k4) {
            const float4 w0 = wp[(0 * NK4_2 + k4) * LL + j];
            const float4 w1 = wp[(1 * NK4_2 + k4) * LL + j];
            const float4 w2 = wp[(2 * NK4_2 + k4) * LL + j];
            const float w0a[4] = {w0.x, w0.y, w0.z, w0.w};
            const float w1a[4] = {w1.x, w1.y, w1.z, w1.w};
            const float w2a[4] = {w2.x, w2.y, w2.z, w2.w};
            #pragma unroll
            for (int c = 0; c < 4; ++c) {
                const float2 v2 = *(const float2*)&ah[k4 * 4 + c][g * 2];
                a0[0] = fmaf(w0a[c], v2.x, a0[0]);
                a1[0] = fmaf(w1a[c], v2.x, a1[0]);
                a2[0] = fmaf(w2a[c], v2.x, a2[0]);
                a0[1] = fmaf(w0a[c], v2.y, a0[1]);
                a1[1] = fmaf(w1a[c], v2.y, a1[1]);
                a2[1] = fmaf(w2a[c], v2.y, a2[1]);
            }
        }
        #pragma unroll
        for (int s = 0; s < 2; ++s) {
            gates[g * 3 + 0][s][j] = a0[s];
            gates[g * 3 + 1][s][j] = a1[s];
            gates[g * 3 + 2][s][j] = a2[s];
        }
        __syncthreads();

        const int total = nact * LL;
        for (int o = tid; o < total; o += 256) {
            const int s = o >> 7, jj = o & 127;
            const int node = nodes_sh[s];
            const float ir = gates[0][s][jj] + bih[jj];
            const float iz = gates[1][s][jj] + bih[LL + jj];
            const float inn = gates[2][s][jj] + bih[2 * LL + jj];
            const float hr = gates[3][s][jj] + bhh[jj];
            const float hz = gates[4][s][jj] + bhh[LL + jj];
            const float hn = gates[5][s][jj] + bhh[2 * LL + jj];
            const float r = 1.0f / (1.0f + __expf(-(ir + hr)));
            const float z = 1.0f / (1.0f + __expf(-(iz + hz)));
            const float n = tanhf(inn + r * hn);
            const float h = memory[(size_t)node * LL + jj];
            out[(size_t)node * LL + jj] = (1.0f - z) * n + z * h;
        }
    }
}

// ---------------------------------------------------------------------------
extern "C" void kernel_launch(void* const* d_in, const int* in_sizes, int n_in,
                              void* d_out, int out_size, void* d_ws, size_t ws_size,
                              hipStream_t stream) {
    const float* x        = (const float*)d_in[0];
    const float* memory   = (const float*)d_in[1];
    const float* delta_t  = (const float*)d_in[2];
    const float* src_w1   = (const float*)d_in[3];
    const float* src_b1   = (const float*)d_in[4];
    const float* src_w2   = (const float*)d_in[5];
    const float* src_b2   = (const float*)d_in[6];
    const float* tar_w1   = (const float*)d_in[7];
    const float* tar_b1   = (const float*)d_in[8];
    const float* tar_w2   = (const float*)d_in[9];
    const float* tar_b2   = (const float*)d_in[10];
    const float* gru_wih  = (const float*)d_in[11];
    const float* gru_whh  = (const float*)d_in[12];
    const float* gru_bih  = (const float*)d_in[13];
    const float* gru_bhh  = (const float*)d_in[14];
    const int*   source   = (const int*)d_in[15];
    const int*   target   = (const int*)d_in[16];

    float* out = (float*)d_out;
    float* ws  = (float*)d_ws;

    // 1) prep: zero accumulators + arrive counter, pack all weights
    prep_kernel<<<512, 256, 0, stream>>>(
        src_w1, tar_w1, src_w2, tar_w2, gru_wih, gru_whh, ws);

    // 2) fused edge + barrier + copy/GRU
    fused_kernel<<<NBLK, 256, 0, stream>>>(
        x, memory, delta_t, src_b1, src_b2, tar_b1, tar_b2,
        gru_bih, gru_bhh, source, target, ws, out);
}

// Round 11
// 36.798 us; speedup vs baseline: 1.7383x; 1.7383x over previous
//
#include <hip/hip_runtime.h>
#include <math.h>

// Problem constants
#define BB 512      // batch (edges)
#define NN 4096     // nodes
#define LL 128      // feature dim
#define IN_DIM 385  // 3*L + ND
#define NK4_1 97    // ceil(IN_DIM/4) k-groups, layer 1
#define NK4_2 32    // LL/4 k-groups, layer 2 / GRU
#define EPB 2       // edges per block (edge phase)
#define GPB 4       // nodes per block (gru kernel)

// ---------------------------------------------------------------------------
// Workspace layout (float offsets, float4-aligned)
// ---------------------------------------------------------------------------
#define OFF_MSG   0                           // msg_sum (N*L)
#define OFF_CNT   (OFF_MSG + NN * LL)         // cnt (N)
#define OFF_COUNT (OFF_CNT + NN)              // seen_count (1 int) + pad
#define OFF_LIST  (OFF_COUNT + 4)             // seen list (1024 ints)
#define OFF_W1PS  529416                      // src_w1 packed f4[k4*128+j]
#define OFF_W1PT  (OFF_W1PS + NK4_1 * LL * 4)
#define OFF_W2PS  (OFF_W1PT + NK4_1 * LL * 4)
#define OFF_W2PT  (OFF_W2PS + NK4_2 * LL * 4)
#define OFF_WIHP  (OFF_W2PT + NK4_2 * LL * 4) // f4[(gate*32+k4)*128+j]
#define OFF_WHHP  (OFF_WIHP + 3 * NK4_2 * LL * 4)

// ---------------------------------------------------------------------------
// Prep: zero accumulators + pack w1 (odd stride) and w2. GRU weight packing
// moved to the edge kernel's extra blocks (only kernel 3 consumes it).
// ---------------------------------------------------------------------------
__global__ __launch_bounds__(256) void prep_kernel(
    const float* __restrict__ sw1, const float* __restrict__ tw1,
    const float* __restrict__ sw2, const float* __restrict__ tw2,
    float* __restrict__ ws)
{
    const int i = blockIdx.x * 256 + threadIdx.x;
    const int stride = gridDim.x * 256;

    float4* msg4 = (float4*)(ws + OFF_MSG);
    const float4 z4 = make_float4(0.f, 0.f, 0.f, 0.f);
    for (int idx = i; idx < NN * LL / 4; idx += stride)
        msg4[idx] = z4;
    for (int idx = i; idx < NN; idx += stride)
        ws[OFF_CNT + idx] = 0.0f;
    if (i == 0)
        ((int*)ws)[OFF_COUNT] = 0;

    float4* w1ps = (float4*)(ws + OFF_W1PS);
    float4* w1pt = (float4*)(ws + OFF_W1PT);
    for (int idx = i; idx < NK4_1 * LL; idx += stride) {
        const int k4 = idx >> 7, j = idx & 127;
        const int k = k4 * 4;
        float4 a, b;
        a.x = sw1[j * IN_DIM + k];     b.x = tw1[j * IN_DIM + k];
        a.y = (k + 1 < IN_DIM) ? sw1[j * IN_DIM + k + 1] : 0.f;
        b.y = (k + 1 < IN_DIM) ? tw1[j * IN_DIM + k + 1] : 0.f;
        a.z = (k + 2 < IN_DIM) ? sw1[j * IN_DIM + k + 2] : 0.f;
        b.z = (k + 2 < IN_DIM) ? tw1[j * IN_DIM + k + 2] : 0.f;
        a.w = (k + 3 < IN_DIM) ? sw1[j * IN_DIM + k + 3] : 0.f;
        b.w = (k + 3 < IN_DIM) ? tw1[j * IN_DIM + k + 3] : 0.f;
        w1ps[idx] = a; w1pt[idx] = b;
    }
    float4* w2ps = (float4*)(ws + OFF_W2PS);
    float4* w2pt = (float4*)(ws + OFF_W2PT);
    for (int idx = i; idx < NK4_2 * LL; idx += stride) {
        const int k4 = idx >> 7, j = idx & 127;
        const int k = k4 * 4;
        w2ps[idx] = make_float4(sw2[j * LL + k], sw2[j * LL + k + 1],
                                sw2[j * LL + k + 2], sw2[j * LL + k + 3]);
        w2pt[idx] = make_float4(tw2[j * LL + k], tw2[j * LL + k + 1],
                                tw2[j * LL + k + 2], tw2[j * LL + k + 3]);
    }
}

// ---------------------------------------------------------------------------
// FMA helper: one packed-weight f4 against two edges' input f4s.
#define STEP(w, iA, iB)                                   \
    a0 = fmaf((w).x, (iA).x, a0); a1 = fmaf((w).x, (iB).x, a1); \
    a0 = fmaf((w).y, (iA).y, a0); a1 = fmaf((w).y, (iB).y, a1); \
    a0 = fmaf((w).z, (iA).z, a0); a1 = fmaf((w).z, (iB).z, a1); \
    a0 = fmaf((w).w, (iA).w, a0); a1 = fmaf((w).w, (iB).w, a1);

// ---------------------------------------------------------------------------
// Edge messages: 512 threads, 4-way k-split (groups g=0..3), EPB=2 edges per
// block; blocks 512..527 copy memory->out; 528..551 pack GRU weights (used
// only by the next kernel).
// ---------------------------------------------------------------------------
__global__ __launch_bounds__(512) void edge_msg_kernel(
    const float* __restrict__ x,        // (B, N, 1)
    const float* __restrict__ memory,   // (N, L)
    const float* __restrict__ delta_t,  // (B, N, L)
    const float* __restrict__ sb1, const float* __restrict__ sb2,
    const float* __restrict__ tb1, const float* __restrict__ tb2,
    const float* __restrict__ wih, const float* __restrict__ whh,
    const int* __restrict__ source, const int* __restrict__ target,
    float* __restrict__ ws, float* __restrict__ out)
{
    const int tid = threadIdx.x;

    // ---- copy blocks ----
    if (blockIdx.x >= 512) {
        if (blockIdx.x < 528) {
            const int cb = blockIdx.x - 512;
            float4* out4 = (float4*)out;
            const float4* mem4 = (const float4*)memory;
            for (int idx = cb * 512 + tid; idx < NN * LL / 4; idx += 16 * 512)
                out4[idx] = mem4[idx];
        } else {
            // ---- GRU weight packing (consumed only by gru_kernel) ----
            const int idx = (blockIdx.x - 528) * 512 + tid;  // [0, 12288)
            const int j = idx & 127;
            const int gk = idx >> 7;            // gate*32 + k4
            const int gate = gk >> 5, k4 = gk & 31;
            const int row = gate * LL + j, k = k4 * 4;
            ((float4*)(ws + OFF_WIHP))[idx] =
                make_float4(wih[row * LL + k], wih[row * LL + k + 1],
                            wih[row * LL + k + 2], wih[row * LL + k + 3]);
            ((float4*)(ws + OFF_WHHP))[idx] =
                make_float4(whh[row * LL + k], whh[row * LL + k + 1],
                            whh[row * LL + k + 2], whh[row * LL + k + 3]);
        }
        return;
    }

    // ---- edge blocks ----
    const int side  = blockIdx.x & 1;
    const int chunk = blockIdx.x >> 1;
    const int g     = tid >> 7;              // k-split group 0..3
    const int j     = tid & 127;             // output feature

    const int eg0 = chunk * EPB, eg1 = eg0 + 1;
    const int s0 = source[eg0], t0 = target[eg0];
    const int s1 = source[eg1], t1 = target[eg1];
    const int node0  = side ? t0 : s0, other0 = side ? s0 : t0;
    const int node1  = side ? t1 : s1, other1 = side ? s1 : t1;

    __shared__ float h1[LL][EPB];
    __shared__ float part1[4][EPB][LL];
    __shared__ float part2[4][EPB][LL];

    const float4* w1p = (const float4*)(ws + (side ? OFF_W1PT : OFF_W1PS));
    const float4* w2p = (const float4*)(ws + (side ? OFF_W2PT : OFF_W2PS));
    const float* b1  = side ? tb1 : sb1;
    const float* b2  = side ? tb2 : sb2;

    // Layer 1: segments (k4): [0,32)=mem[node], [32,64)=mem[other],
    // [64,96)=delta_t, 96=x. Groups: g0 [0,24), g1 [24,48), g2 [48,72),
    // g3 [72,97) -- balanced 24/24/24/25.
    {
        float a0 = 0.f, a1 = 0.f;
        const float* nA = memory + (size_t)node0 * LL;
        const float* nB = memory + (size_t)node1 * LL;
        const float* oA = memory + (size_t)other0 * LL;
        const float* oB = memory + (size_t)other1 * LL;
        const float* dA = delta_t + ((size_t)eg0 * NN + node0) * LL;
        const float* dB = delta_t + ((size_t)eg1 * NN + node1) * LL;

        if (g == 0) {
            #pragma unroll 4
            for (int k4 = 0; k4 < 24; ++k4) {
                const float4 w = w1p[k4 * LL + j];
                const float4 iA = *(const float4*)(nA + 4 * k4);
                const float4 iB = *(const float4*)(nB + 4 * k4);
                STEP(w, iA, iB)
            }
        } else if (g == 1) {
            #pragma unroll 4
            for (int k4 = 24; k4 < 32; ++k4) {
                const float4 w = w1p[k4 * LL + j];
                const float4 iA = *(const float4*)(nA + 4 * k4);
                const float4 iB = *(const float4*)(nB + 4 * k4);
                STEP(w, iA, iB)
            }
            #pragma unroll 4
            for (int k4 = 32; k4 < 48; ++k4) {
                const float4 w = w1p[k4 * LL + j];
                const float4 iA = *(const float4*)(oA + 4 * (k4 - 32));
                const float4 iB = *(const float4*)(oB + 4 * (k4 - 32));
                STEP(w, iA, iB)
            }
        } else if (g == 2) {
            #pragma unroll 4
            for (int k4 = 48; k4 < 64; ++k4) {
                const float4 w = w1p[k4 * LL + j];
                const float4 iA = *(const float4*)(oA + 4 * (k4 - 32));
                const float4 iB = *(const float4*)(oB + 4 * (k4 - 32));
                STEP(w, iA, iB)
            }
            #pragma unroll 4
            for (int k4 = 64; k4 < 72; ++k4) {
                const float4 w = w1p[k4 * LL + j];
                const float4 iA = *(const float4*)(dA + 4 * (k4 - 64));
                const float4 iB = *(const float4*)(dB + 4 * (k4 - 64));
                STEP(w, iA, iB)
            }
        } else {
            #pragma unroll 4
            for (int k4 = 72; k4 < 96; ++k4) {
                const float4 w = w1p[k4 * LL + j];
                const float4 iA = *(const float4*)(dA + 4 * (k4 - 64));
                const float4 iB = *(const float4*)(dB + 4 * (k4 - 64));
                STEP(w, iA, iB)
            }
            {   // k = 384: x (w1p[96].yzw zero-padded)
                const float4 w = w1p[96 * LL + j];
                a0 = fmaf(w.x, x[(size_t)eg0 * NN + node0], a0);
                a1 = fmaf(w.x, x[(size_t)eg1 * NN + node1], a1);
            }
        }
        part1[g][0][j] = a0;
        part1[g][1][j] = a1;
    }
    __syncthreads();

    // Combine + bias + relu; groups 0,1 finish edges 0,1.
    if (g < EPB) {
        const float v = part1[0][g][j] + part1[1][g][j]
                      + part1[2][g][j] + part1[3][g][j] + b1[j];
        h1[j][g] = fmaxf(v, 0.0f);
    }
    __syncthreads();

    // Layer 2: 4-way k-split, 8 k4 per group.
    {
        const int k40 = g * 8, k41 = k40 + 8;
        float a0 = 0.f, a1 = 0.f;
        #pragma unroll 4
        for (int k4 = k40; k4 < k41; ++k4) {
            const float4 w  = w2p[k4 * LL + j];
            const float4 h0 = *(const float4*)&h1[k4 * 4][0];
            const float4 h2 = *(const float4*)&h1[k4 * 4 + 2][0];
            a0 = fmaf(w.x, h0.x, a0); a1 = fmaf(w.x, h0.y, a1);
            a0 = fmaf(w.y, h0.z, a0); a1 = fmaf(w.y, h0.w, a1);
            a0 = fmaf(w.z, h2.x, a0); a1 = fmaf(w.z, h2.y, a1);
            a0 = fmaf(w.w, h2.z, a0); a1 = fmaf(w.w, h2.w, a1);
        }
        part2[g][0][j] = a0;
        part2[g][1][j] = a1;
    }
    __syncthreads();

    // Final message; atomic segment-sum. Groups 0,1 finish edges 0,1.
    if (g < EPB) {
        const int node = g ? node1 : node0;
        const float m = part2[0][g][j] + part2[1][g][j]
                      + part2[2][g][j] + part2[3][g][j] + b2[j];
        atomicAdd(ws + OFF_MSG + (size_t)node * LL + j, m);
    }
    if (tid < EPB) {
        const int node = tid ? node1 : node0;
        const float old = atomicAdd(ws + OFF_CNT + node, 1.0f);
        if (old == 0.0f) {
            const int pos = atomicAdd((int*)ws + OFF_COUNT, 1);
            ((int*)ws)[OFF_LIST + pos] = node;
        }
    }
}

// ---------------------------------------------------------------------------
// GRU over the compact seen list. 512 threads, 4-way split: gsel = g>>1
// (0: wih vs raw msg_sum, end-scaled by 1/cnt; 1: whh vs h), khalf = g&1.
// GPB=4 nodes/block, 256 blocks. Block-uniform operand reads, packed weights.
// ---------------------------------------------------------------------------
__global__ __launch_bounds__(512) void gru_kernel(
    const float* __restrict__ memory,
    const float* __restrict__ bih, const float* __restrict__ bhh,
    const float* __restrict__ ws, float* __restrict__ out)
{
    const int tid = threadIdx.x;
    const int g = tid >> 7, j = tid & 127;
    const int gsel = g >> 1, khalf = g & 1;
    const int scount = ((const int*)ws)[OFF_COUNT];
    const int base = blockIdx.x * GPB;
    if (base >= scount) return;
    const int nact = min(GPB, scount - base);

    __shared__ float gpart[4][3][GPB][LL];   // [group][gate][slot][j] 24 KB
    __shared__ int   nodes_sh[GPB];

    int nd[GPB];
    #pragma unroll
    for (int s = 0; s < GPB; ++s)
        nd[s] = (base + s < scount) ? ((const int*)ws)[OFF_LIST + base + s]
                                    : ((const int*)ws)[OFF_LIST + base];
    if (tid < GPB) nodes_sh[tid] = nd[tid];

    const float* op[GPB];
    float rc[GPB] = {1.f, 1.f, 1.f, 1.f};
    #pragma unroll
    for (int s = 0; s < GPB; ++s) {
        if (gsel == 0) {
            op[s] = ws + OFF_MSG + (size_t)nd[s] * LL;
            rc[s] = 1.0f / ws[OFF_CNT + nd[s]];
        } else {
            op[s] = memory + (size_t)nd[s] * LL;
        }
    }

    const float4* wp = (const float4*)(ws + (gsel ? OFF_WHHP : OFF_WIHP));
    float a0[GPB] = {}, a1[GPB] = {}, a2[GPB] = {};
    const int k40 = khalf * 16;
    #pragma unroll 2
    for (int k4 = k40; k4 < k40 + 16; ++k4) {
        const float4 w0 = wp[(0 * NK4_2 + k4) * LL + j];
        const float4 w1 = wp[(1 * NK4_2 + k4) * LL + j];
        const float4 w2 = wp[(2 * NK4_2 + k4) * LL + j];
        #pragma unroll
        for (int s = 0; s < GPB; ++s) {
            const float4 v = *(const float4*)(op[s] + 4 * k4);
            a0[s] = fmaf(w0.x, v.x, a0[s]); a0[s] = fmaf(w0.y, v.y, a0[s]);
            a0[s] = fmaf(w0.z, v.z, a0[s]); a0[s] = fmaf(w0.w, v.w, a0[s]);
            a1[s] = fmaf(w1.x, v.x, a1[s]); a1[s] = fmaf(w1.y, v.y, a1[s]);
            a1[s] = fmaf(w1.z, v.z, a1[s]); a1[s] = fmaf(w1.w, v.w, a1[s]);
            a2[s] = fmaf(w2.x, v.x, a2[s]); a2[s] = fmaf(w2.y, v.y, a2[s]);
            a2[s] = fmaf(w2.z, v.z, a2[s]); a2[s] = fmaf(w2.w, v.w, a2[s]);
        }
    }
    #pragma unroll
    for (int s = 0; s < GPB; ++s) {
        gpart[g][0][s][j] = a0[s] * rc[s];
        gpart[g][1][s][j] = a1[s] * rc[s];
        gpart[g][2][s][j] = a2[s] * rc[s];
    }
    __syncthreads();

    // Finalize: combine k-halves; h re-read coalesced from global (L2 hit).
    const int total = nact * LL;
    for (int o = tid; o < total; o += 512) {
        const int s = o >> 7, jj = o & 127;
        const int node = nodes_sh[s];
        const float ir = gpart[0][0][s][jj] + gpart[1][0][s][jj] + bih[jj];
        const float iz = gpart[0][1][s][jj] + gpart[1][1][s][jj] + bih[LL + jj];
        const float inn = gpart[0][2][s][jj] + gpart[1][2][s][jj] + bih[2 * LL + jj];
        const float hr = gpart[2][0][s][jj] + gpart[3][0][s][jj] + bhh[jj];
        const float hz = gpart[2][1][s][jj] + gpart[3][1][s][jj] + bhh[LL + jj];
        const float hn = gpart[2][2][s][jj] + gpart[3][2][s][jj] + bhh[2 * LL + jj];
        const float r = 1.0f / (1.0f + __expf(-(ir + hr)));
        const float z = 1.0f / (1.0f + __expf(-(iz + hz)));
        const float n = tanhf(inn + r * hn);
        const float h = memory[(size_t)node * LL + jj];
        out[(size_t)node * LL + jj] = (1.0f - z) * n + z * h;
    }
}

// ---------------------------------------------------------------------------
extern "C" void kernel_launch(void* const* d_in, const int* in_sizes, int n_in,
                              void* d_out, int out_size, void* d_ws, size_t ws_size,
                              hipStream_t stream) {
    const float* x        = (const float*)d_in[0];
    const float* memory   = (const float*)d_in[1];
    const float* delta_t  = (const float*)d_in[2];
    const float* src_w1   = (const float*)d_in[3];
    const float* src_b1   = (const float*)d_in[4];
    const float* src_w2   = (const float*)d_in[5];
    const float* src_b2   = (const float*)d_in[6];
    const float* tar_w1   = (const float*)d_in[7];
    const float* tar_b1   = (const float*)d_in[8];
    const float* tar_w2   = (const float*)d_in[9];
    const float* tar_b2   = (const float*)d_in[10];
    const float* gru_wih  = (const float*)d_in[11];
    const float* gru_whh  = (const float*)d_in[12];
    const float* gru_bih  = (const float*)d_in[13];
    const float* gru_bhh  = (const float*)d_in[14];
    const int*   source   = (const int*)d_in[15];
    const int*   target   = (const int*)d_in[16];

    float* out = (float*)d_out;
    float* ws  = (float*)d_ws;

    // 1) prep: zero accumulators + pack w1/w2 (edge prereqs only)
    prep_kernel<<<256, 256, 0, stream>>>(
        src_w1, tar_w1, src_w2, tar_w2, ws);

    // 2) edge messages (512) + copy (16) + gru-weight pack (24)
    edge_msg_kernel<<<552, 512, 0, stream>>>(
        x, memory, delta_t, src_b1, src_b2, tar_b1, tar_b2,
        gru_wih, gru_whh, source, target, ws, out);

    // 3) GRU over compact seen list
    gru_kernel<<<1024 / GPB, 512, 0, stream>>>(
        memory, gru_bih, gru_bhh, ws, out);
}